// Round 4
// baseline (752.018 us; speedup 1.0000x reference)
//
#include <hip/hip_runtime.h>
#include <hip/hip_bf16.h>
#include <stdint.h>

#define NROWS 131072
#define EPSBN 1e-5f
#define LEAKK 0.33f

typedef __bf16 bf16x8_t __attribute__((ext_vector_type(8)));
typedef float  f32x4_t  __attribute__((ext_vector_type(4)));

__device__ __forceinline__ float leaky_f(float x) { return fmaxf(x, LEAKK * x); }

// LDS-free gather-GEMM conv, software-pipelined 2 deep on the idx->gather chain.
// out[n,d] = sum_k sum_c src[cidxT[k][n],c] * w[k,c,d]; cidxT premasked
// (masked-out -> row NROWS = zeros). Wave tile: 32 rows x 64 cols (acc 2x4).
// Grid 1024 blocks -> 4096 waves -> 4 waves/SIMD (VGPR-capped via launch_bounds).
__global__ __launch_bounds__(256, 4) void conv_kernel(
    const __bf16* __restrict__ src,      // (NROWS+1) x 64, row NROWS = zeros
    const int* __restrict__ cidxT,       // [9][NROWS]
    const __bf16* __restrict__ wt,       // [9][64 d][64 c]
    __bf16* __restrict__ dst,
    float* __restrict__ stat_out)
{
    __shared__ float red[128];

    const int tid  = threadIdx.x;
    const int lane = tid & 63;
    const int wv   = tid >> 6;
    const int quad = lane >> 4;
    const int l15  = lane & 15;
    const int row0 = blockIdx.x << 7;            // 128 rows per block
    const int rbase = row0 + (wv << 5) + l15;    // wave covers 32 rows
    const int boff = quad << 4;                  // byte offset in 64B half-row

    if (tid < 128) red[tid] = 0.f;

    f32x4_t acc[2][4];
#pragma unroll
    for (int mt = 0; mt < 2; ++mt)
#pragma unroll
        for (int nt = 0; nt < 4; ++nt)
            acc[mt][nt] = (f32x4_t){0.f, 0.f, 0.f, 0.f};

    const char* srcb = (const char*)src;
    const char* wtb  = (const char*)wt;

    // pipeline state: af[slot] = A-fragments for iter with parity slot,
    // cx[slot] = row indices for the NEXT gather into af[slot].
    int cx[2][2];
    bf16x8_t af[2][2][2];

#pragma unroll
    for (int mt = 0; mt < 2; ++mt)
        cx[0][mt] = cidxT[rbase + (mt << 4)];                    // k=0 idx
#pragma unroll
    for (int mt = 0; mt < 2; ++mt) {
        const char* p = srcb + ((size_t)cx[0][mt] << 7) + boff;  // k=0 gather
        af[0][mt][0] = *(const bf16x8_t*)(p);
        af[0][mt][1] = *(const bf16x8_t*)(p + 64);
    }
#pragma unroll
    for (int mt = 0; mt < 2; ++mt)
        cx[1][mt] = cidxT[NROWS + rbase + (mt << 4)];            // k=1 idx

#pragma unroll
    for (int k = 0; k < 9; ++k) {
        const int cur = k & 1, nxt = cur ^ 1;
        // B slab k (L1-hot broadcast), needed this iteration
        bf16x8_t bfr[4][2];
#pragma unroll
        for (int nt = 0; nt < 4; ++nt) {
            const char* p = wtb + ((size_t)k << 13)
                          + ((size_t)((nt << 4) + l15) << 7) + boff;
            bfr[nt][0] = *(const bf16x8_t*)(p);
            bfr[nt][1] = *(const bf16x8_t*)(p + 64);
        }
        // gather A for k+1 (indices loaded two iterations ago)
        if (k < 8) {
#pragma unroll
            for (int mt = 0; mt < 2; ++mt) {
                const char* p = srcb + ((size_t)cx[nxt][mt] << 7) + boff;
                af[nxt][mt][0] = *(const bf16x8_t*)(p);
                af[nxt][mt][1] = *(const bf16x8_t*)(p + 64);
            }
        }
        // indices for k+2 (slot cur's indices were consumed last iteration)
        if (k < 7) {
#pragma unroll
            for (int mt = 0; mt < 2; ++mt)
                cx[cur][mt] = cidxT[(k + 2) * NROWS + rbase + (mt << 4)];
        }
        // MFMA on fragments gathered last iteration
#pragma unroll
        for (int ks = 0; ks < 2; ++ks)
#pragma unroll
            for (int mt = 0; mt < 2; ++mt)
#pragma unroll
                for (int nt = 0; nt < 4; ++nt)
                    acc[mt][nt] = __builtin_amdgcn_mfma_f32_16x16x32_bf16(
                        af[cur][mt][ks], bfr[nt][ks], acc[mt][nt], 0, 0, 0);
    }

    // store (D layout: row = quad*4+reg, col = lane&15)
#pragma unroll
    for (int mt = 0; mt < 2; ++mt) {
        int rowb = row0 + (wv << 5) + (mt << 4) + (quad << 2);
#pragma unroll
        for (int nt = 0; nt < 4; ++nt) {
            int col = (nt << 4) + l15;
#pragma unroll
            for (int r = 0; r < 4; ++r)
                dst[((size_t)(rowb + r) << 6) + col] = (__bf16)acc[mt][nt][r];
        }
    }
    // per-channel stats -> quad shuffle -> LDS atomics -> global
#pragma unroll
    for (int nt = 0; nt < 4; ++nt) {
        float s = 0.f, q = 0.f;
#pragma unroll
        for (int mt = 0; mt < 2; ++mt)
#pragma unroll
            for (int r = 0; r < 4; ++r) { float v = acc[mt][nt][r]; s += v; q += v * v; }
        s += __shfl_xor(s, 16); s += __shfl_xor(s, 32);
        q += __shfl_xor(q, 16); q += __shfl_xor(q, 32);
        if (lane < 16) {
            atomicAdd(&red[(nt << 4) + lane], s);
            atomicAdd(&red[64 + (nt << 4) + lane], q);
        }
    }
    __syncthreads();
    if (tid < 128) atomicAdd(&stat_out[tid], red[tid]);
}

// in-place y = leaky(bn(y)) on bf16
__global__ __launch_bounds__(256) void bnact_kernel(
    __bf16* __restrict__ y, const float* __restrict__ stat,
    const float* __restrict__ gamma, const float* __restrict__ beta)
{
    __shared__ float sc[64], sh[64];
    int tid = threadIdx.x;
    if (tid < 64) {
        float m = stat[tid] * (1.f / NROWS);
        float v = stat[64 + tid] * (1.f / NROWS) - m * m;
        float s = gamma[tid] * rsqrtf(v + EPSBN);
        sc[tid] = s;
        sh[tid] = beta[tid] - m * s;
    }
    __syncthreads();
    size_t base = ((((size_t)blockIdx.x << 8) | tid) << 3);
    int c0 = (int)(base & 63);
    bf16x8_t hv = *(bf16x8_t*)(y + base);
#pragma unroll
    for (int j = 0; j < 8; ++j) {
        float f = (float)hv[j];
        f = leaky_f(f * sc[c0 + j] + sh[c0 + j]);
        hv[j] = (__bf16)f;
    }
    *(bf16x8_t*)(y + base) = hv;
}

// x_new = leaky(bn2(z) + x); z bf16, residual stream fp32 (+bf16 mirror)
__global__ __launch_bounds__(256) void resid_kernel(
    const __bf16* __restrict__ z, const float* __restrict__ xin,
    float* __restrict__ xf, __bf16* __restrict__ xh, float* __restrict__ dout,
    const float* __restrict__ stat, const float* __restrict__ gamma,
    const float* __restrict__ beta, int isfinal)
{
    __shared__ float sc[64], sh[64];
    int tid = threadIdx.x;
    if (tid < 64) {
        float m = stat[tid] * (1.f / NROWS);
        float v = stat[64 + tid] * (1.f / NROWS) - m * m;
        float s = gamma[tid] * rsqrtf(v + EPSBN);
        sc[tid] = s;
        sh[tid] = beta[tid] - m * s;
    }
    __syncthreads();
    size_t base = ((((size_t)blockIdx.x << 8) | tid) << 3);
    int c0 = (int)(base & 63);
    bf16x8_t zv = *(const bf16x8_t*)(z + base);
    float4 xa = *(const float4*)(xin + base);
    float4 xb = *(const float4*)(xin + base + 4);
    float o[8];
#pragma unroll
    for (int j = 0; j < 8; ++j) {
        float xv = (j < 4) ? (&xa.x)[j] : (&xb.x)[j - 4];
        o[j] = leaky_f((float)zv[j] * sc[c0 + j] + sh[c0 + j] + xv);
    }
    if (isfinal) {
        *(float4*)(dout + base)     = make_float4(o[0], o[1], o[2], o[3]);
        *(float4*)(dout + base + 4) = make_float4(o[4], o[5], o[6], o[7]);
    } else {
        *(float4*)(xf + base)     = make_float4(o[0], o[1], o[2], o[3]);
        *(float4*)(xf + base + 4) = make_float4(o[4], o[5], o[6], o[7]);
        bf16x8_t h;
#pragma unroll
        for (int j = 0; j < 8; ++j) h[j] = (__bf16)o[j];
        *(bf16x8_t*)(xh + base) = h;
    }
}

// once-per-call prep: features->bf16, weights->transposed bf16, zero stats,
// premasked transposed indices cidxT[k][n] (masked-out -> NROWS), zero
// sentinel rows. Mask encoding detect: center (k=4) always True -> raw byte
// 13 nonzero iff byte-encoded; zero if int32/float32-encoded.
__global__ __launch_bounds__(256) void prep_kernel(
    const float* __restrict__ feat, const float* __restrict__ w1,
    const float* __restrict__ w2, const int* __restrict__ nidx,
    const unsigned char* __restrict__ mraw,
    __bf16* __restrict__ fh, __bf16* __restrict__ yh,
    __bf16* __restrict__ wtp, int* __restrict__ cidxT,
    float* __restrict__ stats)
{
    size_t t = ((size_t)blockIdx.x << 8) | threadIdx.x;
    if (t < 1024) stats[t] = 0.f;
    if (t < 64) {   // zero sentinel rows
        fh[(size_t)NROWS * 64 + t] = (__bf16)0.f;
        yh[(size_t)NROWS * 64 + t] = (__bf16)0.f;
    }
    if (t < 1048576) {  // features: 8 floats -> 8 bf16 per thread
        size_t i = t << 3;
        float4 a = *(const float4*)(feat + i);
        float4 b = *(const float4*)(feat + i + 4);
        bf16x8_t h;
        h[0] = (__bf16)a.x; h[1] = (__bf16)a.y; h[2] = (__bf16)a.z; h[3] = (__bf16)a.w;
        h[4] = (__bf16)b.x; h[5] = (__bf16)b.y; h[6] = (__bf16)b.z; h[7] = (__bf16)b.w;
        *(bf16x8_t*)(fh + i) = h;
    }
    if (t < 294912) {   // wtp[cv][b][k][d][c] = w[b][k][c][d]
        int o = (int)t;
        int c = o & 63, d = (o >> 6) & 63;
        int kk = o >> 12;              // 0..71
        int k = kk % 9, bb = (kk / 9) & 3, cv = kk / 36;
        const float* w = cv ? w2 : w1;
        float v = w[((size_t)((bb * 9 + k) * 64 + c) << 6) + d];
        wtp[o] = (__bf16)v;
    }
    if (t < 1179648) {  // cidxT[k][n]
        int k = (int)(t >> 17), n = (int)(t & 131071);
        bool bytes_enc = (mraw[13] != 0);
        int e = n * 9 + k;
        bool m = bytes_enc ? (mraw[e] != 0) : (((const unsigned int*)mraw)[e] != 0u);
        cidxT[t] = m ? nidx[e] : NROWS;
    }
}

extern "C" void kernel_launch(void* const* d_in, const int* in_sizes, int n_in,
                              void* d_out, int out_size, void* d_ws, size_t ws_size,
                              hipStream_t stream) {
    const float* feat = (const float*)d_in[0];
    const int* nidx = (const int*)d_in[1];
    const unsigned char* mraw = (const unsigned char*)d_in[2];
    const float* w1 = (const float*)d_in[3];
    const float* g1 = (const float*)d_in[4];
    const float* b1 = (const float*)d_in[5];
    const float* w2 = (const float*)d_in[6];
    const float* g2 = (const float*)d_in[7];
    const float* b2 = (const float*)d_in[8];
    float* out = (float*)d_out;

    char* ws = (char*)d_ws;
    float*  xf    = (float*)ws;                        // 33.55 MB fp32 residual
    __bf16* xh    = (__bf16*)(ws + 33554432);          // (N+1) rows bf16 mirror of x
    __bf16* yh    = (__bf16*)(ws + 50331904);          // (N+1) rows bf16 conv1 out
    __bf16* zh    = (__bf16*)(ws + 67109376);          // N rows bf16 conv2 out
    __bf16* wtp   = (__bf16*)(ws + 83886592);          // 0.59 MB transposed weights
    float*  stats = (float*)(ws + 84476416);           // 8 stages x 128 floats
    int*    cidxT = (int*)(ws + 84480512);             // 4.72 MB premasked idx^T

    prep_kernel<<<4608, 256, 0, stream>>>(feat, w1, w2, nidx, mraw,
                                          xh, yh, wtp, cidxT, stats);

    for (int b = 0; b < 4; ++b) {
        conv_kernel<<<1024, 256, 0, stream>>>(
            xh, cidxT, wtp + (size_t)b * 9 * 4096,
            yh, stats + (size_t)(2 * b) * 128);
        bnact_kernel<<<4096, 256, 0, stream>>>(
            yh, stats + (size_t)(2 * b) * 128, g1 + b * 64, b1 + b * 64);
        conv_kernel<<<1024, 256, 0, stream>>>(
            yh, cidxT, wtp + (size_t)(4 + b) * 9 * 4096,
            zh, stats + (size_t)(2 * b + 1) * 128);
        resid_kernel<<<4096, 256, 0, stream>>>(
            zh, (b == 0) ? feat : xf, xf, xh, out,
            stats + (size_t)(2 * b + 1) * 128, g2 + b * 64, b2 + b * 64,
            (b == 3) ? 1 : 0);
    }
}

// Round 5
// 418.224 us; speedup vs baseline: 1.7981x; 1.7981x over previous
//
#include <hip/hip_runtime.h>
#include <hip/hip_bf16.h>
#include <stdint.h>

#define NROWS 131072
#define EPSBN 1e-5f
#define LEAKK 0.33f

typedef __bf16 bf16x8_t __attribute__((ext_vector_type(8)));
typedef float  f32x4_t  __attribute__((ext_vector_type(4)));

__device__ __forceinline__ float leaky_f(float x) { return fmaxf(x, LEAKK * x); }

#define GLDS16(g, l)                                                          \
    __builtin_amdgcn_global_load_lds(                                         \
        (const __attribute__((address_space(1))) void*)(g),                   \
        (__attribute__((address_space(3))) void*)(l), 16, 0, 0)

// Waitcnt immediates (gfx9 encoding: vmcnt[3:0]|[15:14], expcnt[6:4]=7, lgkm[11:8]=15)
#define WAIT_VM18 0x4F72
#define WAIT_VM10 0x0F7A
#define WAIT_VM8  0x0F78
#define WAIT_VM0  0x0F70
#define CFENCE() asm volatile("" ::: "memory")

// Gather-GEMM conv via async global_load_lds pipeline.
// out[n,d] = sum_k sum_c src[cidxT[k][n],c] * w[k,c,d]; cidxT premasked
// (masked-out -> row NROWS = zeros). Block: 256 rows; wave tile 64x64.
// A slab (32KB) + B slab (8KB) double-buffered in LDS, staged by
// global_load_lds with per-lane gather addresses; XOR chunk swizzle
// (slot = chunk ^ (row&7)) keeps ds_read_b128 at 2-way conflicts.
// Hand-scheduled s_waitcnt vmcnt(N) + raw s_barrier (no full drains).
__global__ __launch_bounds__(256, 2) void conv_kernel(
    const __bf16* __restrict__ src,      // (NROWS+1) x 64, row NROWS = zeros
    const int* __restrict__ cidxT,       // [9][NROWS]
    const __bf16* __restrict__ wt,       // [9][64 d][64 c]
    __bf16* __restrict__ dst,
    float* __restrict__ stat_out)
{
    __shared__ char Ab[2][32768];
    __shared__ char Bb[2][8192];

    const int tid  = threadIdx.x;
    const int lane = tid & 63;
    const int wv   = tid >> 6;
    const int quad = lane >> 4;
    const int l15  = lane & 15;
    const int row0 = blockIdx.x << 8;          // 256 rows/block
    const int srow = tid >> 3;                 // staging base row (0..31)
    const int cg   = (tid & 7) ^ (srow & 7);   // swizzled global chunk
    const int ldsl = (tid & 192) << 4;         // wave-uniform lds sub-base
    const int sxor = l15 & 7;

    const char* srcb = (const char*)src;
    const char* wtb  = (const char*)wt;

    f32x4_t acc[4][4];
#pragma unroll
    for (int mt = 0; mt < 4; ++mt)
#pragma unroll
        for (int nt = 0; nt < 4; ++nt)
            acc[mt][nt] = (f32x4_t){0.f, 0.f, 0.f, 0.f};

    int ix[2][8];
    // prologue: idx k=0, idx k=1, wait idx0, stage slab 0
#pragma unroll
    for (int i = 0; i < 8; ++i) ix[0][i] = cidxT[row0 + (i << 5) + srow];
    CFENCE();
#pragma unroll
    for (int i = 0; i < 8; ++i) ix[1][i] = cidxT[NROWS + row0 + (i << 5) + srow];
    CFENCE();
    __builtin_amdgcn_s_waitcnt(WAIT_VM8);      // ix0 ready (ix1 in flight)
#pragma unroll
    for (int i = 0; i < 8; ++i)
        GLDS16(srcb + ((size_t)ix[0][i] << 7) + (cg << 4), &Ab[0][(i << 12) + ldsl]);
#pragma unroll
    for (int i = 0; i < 2; ++i)
        GLDS16(wtb + (((i << 5) + srow) << 7) + (cg << 4), &Bb[0][(i << 12) + ldsl]);
    CFENCE();

#pragma unroll
    for (int k = 0; k < 9; ++k) {
        const int cur = k & 1, nxt = cur ^ 1;
        // a: issue idx(k+2) into the slot freed by stage-k
        if (k < 7) {
#pragma unroll
            for (int i = 0; i < 8; ++i)
                ix[k & 1][i] = cidxT[(k + 2) * NROWS + row0 + (i << 5) + srow];
        }
        CFENCE();
        // b: wait idx(k+1) (leaves stage-k + idx(k+2) in flight)
        if (k < 7)       __builtin_amdgcn_s_waitcnt(WAIT_VM18);
        else if (k == 7) __builtin_amdgcn_s_waitcnt(WAIT_VM10);
        // c: issue stage(k+1)
        if (k < 8) {
            const int* ixu = ix[(k + 1) & 1];
#pragma unroll
            for (int i = 0; i < 8; ++i)
                GLDS16(srcb + ((size_t)ixu[i] << 7) + (cg << 4),
                       &Ab[nxt][(i << 12) + ldsl]);
#pragma unroll
            for (int i = 0; i < 2; ++i)
                GLDS16(wtb + ((size_t)(k + 1) << 13) + (((i << 5) + srow) << 7) + (cg << 4),
                       &Bb[nxt][(i << 12) + ldsl]);
        }
        CFENCE();
        // d: wait stage-k (leaves idx(k+2) + stage(k+1) in flight)
        if (k < 7)       __builtin_amdgcn_s_waitcnt(WAIT_VM18);
        else if (k == 7) __builtin_amdgcn_s_waitcnt(WAIT_VM10);
        else             __builtin_amdgcn_s_waitcnt(WAIT_VM0);
        __builtin_amdgcn_s_barrier();          // e: stage-k visible to all
        // f: fragments + MFMA
        bf16x8_t af[4][2], bq[4][2];
#pragma unroll
        for (int ks = 0; ks < 2; ++ks) {
            const int slot = ((quad | (ks << 2)) ^ sxor) << 4;
#pragma unroll
            for (int mt = 0; mt < 4; ++mt) {
                int m = (wv << 6) + (mt << 4) + l15;
                af[mt][ks] = *(const bf16x8_t*)&Ab[cur][(m << 7) + slot];
            }
#pragma unroll
            for (int nt = 0; nt < 4; ++nt) {
                int d = (nt << 4) + l15;
                bq[nt][ks] = *(const bf16x8_t*)&Bb[cur][(d << 7) + slot];
            }
        }
#pragma unroll
        for (int ks = 0; ks < 2; ++ks)
#pragma unroll
            for (int mt = 0; mt < 4; ++mt)
#pragma unroll
                for (int nt = 0; nt < 4; ++nt)
                    acc[mt][nt] = __builtin_amdgcn_mfma_f32_16x16x32_bf16(
                        af[mt][ks], bq[nt][ks], acc[mt][nt], 0, 0, 0);
        __builtin_amdgcn_s_barrier();          // g: reads done before k+2 overwrite
    }

    // store (D layout: row = quad*4+reg, col = lane&15)
#pragma unroll
    for (int mt = 0; mt < 4; ++mt) {
        int rowb = row0 + (wv << 6) + (mt << 4) + (quad << 2);
#pragma unroll
        for (int nt = 0; nt < 4; ++nt) {
            int col = (nt << 4) + l15;
#pragma unroll
            for (int r = 0; r < 4; ++r)
                dst[((size_t)(rowb + r) << 6) + col] = (__bf16)acc[mt][nt][r];
        }
    }
    // stats; red[] aliased onto Bb[1] (free after k=7 consumption)
    float* red = (float*)Bb[1];
    __syncthreads();
    if (tid < 128) red[tid] = 0.f;
    __syncthreads();
#pragma unroll
    for (int nt = 0; nt < 4; ++nt) {
        float s = 0.f, q = 0.f;
#pragma unroll
        for (int mt = 0; mt < 4; ++mt)
#pragma unroll
            for (int r = 0; r < 4; ++r) { float v = acc[mt][nt][r]; s += v; q += v * v; }
        s += __shfl_xor(s, 16); s += __shfl_xor(s, 32);
        q += __shfl_xor(q, 16); q += __shfl_xor(q, 32);
        if (lane < 16) {
            atomicAdd(&red[(nt << 4) + lane], s);
            atomicAdd(&red[64 + (nt << 4) + lane], q);
        }
    }
    __syncthreads();
    if (tid < 128) atomicAdd(&stat_out[tid], red[tid]);
}

// in-place y = leaky(bn(y)) on bf16
__global__ __launch_bounds__(256) void bnact_kernel(
    __bf16* __restrict__ y, const float* __restrict__ stat,
    const float* __restrict__ gamma, const float* __restrict__ beta)
{
    __shared__ float sc[64], sh[64];
    int tid = threadIdx.x;
    if (tid < 64) {
        float m = stat[tid] * (1.f / NROWS);
        float v = stat[64 + tid] * (1.f / NROWS) - m * m;
        float s = gamma[tid] * rsqrtf(v + EPSBN);
        sc[tid] = s;
        sh[tid] = beta[tid] - m * s;
    }
    __syncthreads();
    size_t base = ((((size_t)blockIdx.x << 8) | tid) << 3);
    int c0 = (int)(base & 63);
    bf16x8_t hv = *(bf16x8_t*)(y + base);
#pragma unroll
    for (int j = 0; j < 8; ++j) {
        float f = (float)hv[j];
        f = leaky_f(f * sc[c0 + j] + sh[c0 + j]);
        hv[j] = (__bf16)f;
    }
    *(bf16x8_t*)(y + base) = hv;
}

// x_new = leaky(bn2(z) + x); z bf16, residual stream fp32 (+bf16 mirror)
__global__ __launch_bounds__(256) void resid_kernel(
    const __bf16* __restrict__ z, const float* __restrict__ xin,
    float* __restrict__ xf, __bf16* __restrict__ xh, float* __restrict__ dout,
    const float* __restrict__ stat, const float* __restrict__ gamma,
    const float* __restrict__ beta, int isfinal)
{
    __shared__ float sc[64], sh[64];
    int tid = threadIdx.x;
    if (tid < 64) {
        float m = stat[tid] * (1.f / NROWS);
        float v = stat[64 + tid] * (1.f / NROWS) - m * m;
        float s = gamma[tid] * rsqrtf(v + EPSBN);
        sc[tid] = s;
        sh[tid] = beta[tid] - m * s;
    }
    __syncthreads();
    size_t base = ((((size_t)blockIdx.x << 8) | tid) << 3);
    int c0 = (int)(base & 63);
    bf16x8_t zv = *(const bf16x8_t*)(z + base);
    float4 xa = *(const float4*)(xin + base);
    float4 xb = *(const float4*)(xin + base + 4);
    float o[8];
#pragma unroll
    for (int j = 0; j < 8; ++j) {
        float xv = (j < 4) ? (&xa.x)[j] : (&xb.x)[j - 4];
        o[j] = leaky_f((float)zv[j] * sc[c0 + j] + sh[c0 + j] + xv);
    }
    if (isfinal) {
        *(float4*)(dout + base)     = make_float4(o[0], o[1], o[2], o[3]);
        *(float4*)(dout + base + 4) = make_float4(o[4], o[5], o[6], o[7]);
    } else {
        *(float4*)(xf + base)     = make_float4(o[0], o[1], o[2], o[3]);
        *(float4*)(xf + base + 4) = make_float4(o[4], o[5], o[6], o[7]);
        bf16x8_t h;
#pragma unroll
        for (int j = 0; j < 8; ++j) h[j] = (__bf16)o[j];
        *(bf16x8_t*)(xh + base) = h;
    }
}

// once-per-call prep: features->bf16, weights->transposed bf16, zero stats,
// premasked transposed indices cidxT[k][n] (masked-out -> NROWS), zero
// sentinel rows. Mask encoding detect: center (k=4) always True -> raw byte
// 13 nonzero iff byte-encoded; zero if int32/float32-encoded.
__global__ __launch_bounds__(256) void prep_kernel(
    const float* __restrict__ feat, const float* __restrict__ w1,
    const float* __restrict__ w2, const int* __restrict__ nidx,
    const unsigned char* __restrict__ mraw,
    __bf16* __restrict__ fh, __bf16* __restrict__ yh,
    __bf16* __restrict__ wtp, int* __restrict__ cidxT,
    float* __restrict__ stats)
{
    size_t t = ((size_t)blockIdx.x << 8) | threadIdx.x;
    if (t < 1024) stats[t] = 0.f;
    if (t < 64) {   // zero sentinel rows
        fh[(size_t)NROWS * 64 + t] = (__bf16)0.f;
        yh[(size_t)NROWS * 64 + t] = (__bf16)0.f;
    }
    if (t < 1048576) {  // features: 8 floats -> 8 bf16 per thread
        size_t i = t << 3;
        float4 a = *(const float4*)(feat + i);
        float4 b = *(const float4*)(feat + i + 4);
        bf16x8_t h;
        h[0] = (__bf16)a.x; h[1] = (__bf16)a.y; h[2] = (__bf16)a.z; h[3] = (__bf16)a.w;
        h[4] = (__bf16)b.x; h[5] = (__bf16)b.y; h[6] = (__bf16)b.z; h[7] = (__bf16)b.w;
        *(bf16x8_t*)(fh + i) = h;
    }
    if (t < 294912) {   // wtp[cv][b][k][d][c] = w[b][k][c][d]
        int o = (int)t;
        int c = o & 63, d = (o >> 6) & 63;
        int kk = o >> 12;              // 0..71
        int k = kk % 9, bb = (kk / 9) & 3, cv = kk / 36;
        const float* w = cv ? w2 : w1;
        float v = w[((size_t)((bb * 9 + k) * 64 + c) << 6) + d];
        wtp[o] = (__bf16)v;
    }
    if (t < 1179648) {  // cidxT[k][n]
        int k = (int)(t >> 17), n = (int)(t & 131071);
        bool bytes_enc = (mraw[13] != 0);
        int e = n * 9 + k;
        bool m = bytes_enc ? (mraw[e] != 0) : (((const unsigned int*)mraw)[e] != 0u);
        cidxT[t] = m ? nidx[e] : NROWS;
    }
}

extern "C" void kernel_launch(void* const* d_in, const int* in_sizes, int n_in,
                              void* d_out, int out_size, void* d_ws, size_t ws_size,
                              hipStream_t stream) {
    const float* feat = (const float*)d_in[0];
    const int* nidx = (const int*)d_in[1];
    const unsigned char* mraw = (const unsigned char*)d_in[2];
    const float* w1 = (const float*)d_in[3];
    const float* g1 = (const float*)d_in[4];
    const float* b1 = (const float*)d_in[5];
    const float* w2 = (const float*)d_in[6];
    const float* g2 = (const float*)d_in[7];
    const float* b2 = (const float*)d_in[8];
    float* out = (float*)d_out;

    char* ws = (char*)d_ws;
    float*  xf    = (float*)ws;                        // 33.55 MB fp32 residual
    __bf16* xh    = (__bf16*)(ws + 33554432);          // (N+1) rows bf16 mirror of x
    __bf16* yh    = (__bf16*)(ws + 50331904);          // (N+1) rows bf16 conv1 out
    __bf16* zh    = (__bf16*)(ws + 67109376);          // N rows bf16 conv2 out
    __bf16* wtp   = (__bf16*)(ws + 83886592);          // 0.59 MB transposed weights
    float*  stats = (float*)(ws + 84476416);           // 8 stages x 128 floats
    int*    cidxT = (int*)(ws + 84480512);             // 4.72 MB premasked idx^T

    prep_kernel<<<4608, 256, 0, stream>>>(feat, w1, w2, nidx, mraw,
                                          xh, yh, wtp, cidxT, stats);

    for (int b = 0; b < 4; ++b) {
        conv_kernel<<<512, 256, 0, stream>>>(
            xh, cidxT, wtp + (size_t)b * 9 * 4096,
            yh, stats + (size_t)(2 * b) * 128);
        bnact_kernel<<<4096, 256, 0, stream>>>(
            yh, stats + (size_t)(2 * b) * 128, g1 + b * 64, b1 + b * 64);
        conv_kernel<<<512, 256, 0, stream>>>(
            yh, cidxT, wtp + (size_t)(4 + b) * 9 * 4096,
            zh, stats + (size_t)(2 * b + 1) * 128);
        resid_kernel<<<4096, 256, 0, stream>>>(
            zh, (b == 0) ? feat : xf, xf, xh, out,
            stats + (size_t)(2 * b + 1) * 128, g2 + b * 64, b2 + b * 64,
            (b == 3) ? 1 : 0);
    }
}